// Round 5
// baseline (150.404 us; speedup 1.0000x reference)
//
#include <hip/hip_runtime.h>
#include <hip/hip_bf16.h>

// ---------------------------------------------------------------------------
// TwoSimplicialAttention  (B=2, T=192, C=512, H=8, D=64)
// R9: attn wave decomposition changed from (all-j x k/4) to (j/2 x k/2):
//     each wave: 6 jt, 24 ksteps. k1f shrinks 96->48 regs, freeing room to
//     hoist the 12 kstep-invariant V1 PV-fragments (48 regs) into registers
//     -- all in-loop V1 LDS reads vanish (they were on the PV critical path
//     every pair). V1 LDS staging deleted (vf loaded once from global, L2-hot).
//     LDS 41984 -> 16640 (reduction-sized). Same MFMA/exp counts per wave.
//     Cross-wave reduction unchanged (sums (jh,kh) partials).
//     launch_bounds(256,2): occupancy is register-bound at 2 waves/EU
//     (512-reg/EU pool); this round attacks chain latency, not occupancy.
// ---------------------------------------------------------------------------

typedef float  v4f __attribute__((ext_vector_type(4)));
typedef short  v8s __attribute__((ext_vector_type(8)));

__device__ __forceinline__ unsigned short f2bf(float f) {
  unsigned u = __float_as_uint(f);
  u += 0x7fffu + ((u >> 16) & 1u);       // RNE
  return (unsigned short)(u >> 16);
}
__device__ __forceinline__ float bf2f(unsigned short b) {
  return __uint_as_float(((unsigned)b) << 16);
}
__device__ __forceinline__ unsigned pack_bf16(float lo, float hi) {
  __hip_bfloat162 t = __float22bfloat162_rn(float2{lo, hi});
  union { __hip_bfloat162 b; unsigned u; } cv;
  cv.b = t;
  return cv.u;
}

#if __has_builtin(__builtin_amdgcn_exp2f)
#define EXP2F(x) __builtin_amdgcn_exp2f(x)
#else
#define EXP2F(x) exp2f(x)
#endif

#define MFMA32(a, b, c) __builtin_amdgcn_mfma_f32_16x16x32_bf16((a), (b), (c), 0, 0, 0)

// q scale = D^-0.5 * log2(e)
#define QSCALE 0.18033688011112042f

// ws layout, floats (wsf):
//   qs   [16][192][64]        @ 0        (q * 0.125*log2e, fp32)
//   v2p  [16][192][16][4]     @ 196608   ([.][k][c][r] = v2[d=c+16r], fp32)
//   accp [16][12][4][16][64]  @ 393216
//   Sp   [16][12][4][16]      @ 1179648  (total fp32: 1191936)
// ws layout, ushort (wsh = wsf + 1191936):
//   k1b  [16][192][64]  @ 0
//   k2b  [16][192][64]  @ 196608
//   v1t  [16][64][192]  @ 393216   (columns PERMUTED within 32-chunks)
//   xh   [384][512]     @ 589824      xl @ 786432
//   Wth  [2560][512]    @ 983040      Wtl @ 2293760   (W_in^T, k-major)
//   Woth [512][512]     @ 3604480     Wotl @ 3866624  (W_out^T, k-major)
//   oh   [384][512]     @ 4128768     ol  @ 4325376   (normalized out)

#define XH_OFF   589824
#define XL_OFF   786432
#define WTH_OFF  983040
#define WTL_OFF  2293760
#define WOTH_OFF 3604480
#define WOTL_OFF 3866624
#define OH_OFF   4128768
#define OL_OFF   4325376

// V1 column permutation within a 32-chunk: position p' for j-offset w5:
//   p' = ((w5>>2)&3)<<3 | (w5&3)<<1 | ((w5>>4)&1)
__device__ __forceinline__ int v1perm(int t) {
  return (t & ~31) | (((t >> 2) & 3) << 3) | ((t & 3) << 1) | ((t >> 4) & 1);
}

// ------------------------------ Phase 0: prep ------------------------------
// grid 864: [0,640) W_in transpose+split (64n x 32k tiles), [640,768) W_out,
// [768,864) x hi/lo split. W goes through LDS so global writes are dense.
__global__ __launch_bounds__(256) void prep_kernel(
    const float* __restrict__ x, const float* __restrict__ Win,
    const float* __restrict__ Wout, unsigned short* __restrict__ wsh) {
  __shared__ float tile[32 * 65];
  const int bi = blockIdx.x, t = threadIdx.x;
  if (bi < 768) {
    const float* W; unsigned short *Th, *Tl; int R, n0, k0;
    if (bi < 640) {
      W = Win; Th = wsh + WTH_OFF; Tl = wsh + WTL_OFF; R = 2560;
      n0 = (bi % 40) << 6; k0 = (bi / 40) << 5;
    } else {
      const int idx = bi - 640;
      W = Wout; Th = wsh + WOTH_OFF; Tl = wsh + WOTL_OFF; R = 512;
      n0 = (idx & 7) << 6; k0 = (idx >> 3) << 5;
    }
    // phase 1: coalesced reads -> LDS [k][n] (pad 65)
    const int n = t & 63, kq = (t >> 6) * 8;
#pragma unroll
    for (int j = 0; j < 8; ++j)
      tile[(kq + j) * 65 + n] = W[(k0 + kq + j) * R + n0 + n];
    __syncthreads();
    // phase 2: k-contig hi/lo writes (dense 64B lines)
    const int n2 = t >> 2, ks = (t & 3) * 8;
    union { uint4 u; unsigned short us[8]; } ph, pl;
#pragma unroll
    for (int j = 0; j < 8; ++j) {
      const float v = tile[(ks + j) * 65 + n2];
      const unsigned short h = f2bf(v);
      ph.us[j] = h;
      pl.us[j] = f2bf(v - bf2f(h));
    }
    *(uint4*)(Th + (n0 + n2) * 512 + k0 + ks) = ph.u;
    *(uint4*)(Tl + (n0 + n2) * 512 + k0 + ks) = pl.u;
  } else {
    const int flat = ((bi - 768) * 256 + t) * 8;
    const v4f v0 = *(const v4f*)(x + flat);
    const v4f v1 = *(const v4f*)(x + flat + 4);
    union { uint4 u; unsigned short us[8]; } ph, pl;
#pragma unroll
    for (int j = 0; j < 4; ++j) {
      unsigned short h = f2bf(v0[j]);
      ph.us[j] = h; pl.us[j] = f2bf(v0[j] - bf2f(h));
      h = f2bf(v1[j]);
      ph.us[4 + j] = h; pl.us[4 + j] = f2bf(v1[j] - bf2f(h));
    }
    *(uint4*)(wsh + XH_OFF + flat) = ph.u;
    *(uint4*)(wsh + XL_OFF + flat) = pl.u;
  }
}

// ------------------------------ Phase 1: proj (bf16x3 MFMA) ----------------
// grid 960 x 64thr: 1 wave/block, 32x32 C-tile, prefetch depth 2.
__global__ __launch_bounds__(64) void proj_kernel(
    const unsigned short* __restrict__ wsh, const float* __restrict__ bin,
    float* __restrict__ wsf, unsigned short* __restrict__ wshd) {
  const int lane = threadIdx.x;
  const int c = lane & 15, q = lane >> 4;
  const int bm = blockIdx.x % 12, bn = blockIdx.x / 12;

  const unsigned short* base[8];
  base[0] = wsh + XH_OFF + (bm * 32 + c) * 512 + (q << 3);
  base[1] = base[0] + 16 * 512;
  base[2] = wsh + XL_OFF + (bm * 32 + c) * 512 + (q << 3);
  base[3] = base[2] + 16 * 512;
  base[4] = wsh + WTH_OFF + (bn * 32 + c) * 512 + (q << 3);
  base[5] = base[4] + 16 * 512;
  base[6] = wsh + WTL_OFF + (bn * 32 + c) * 512 + (q << 3);
  base[7] = base[6] + 16 * 512;

  const v4f z = {0.f, 0.f, 0.f, 0.f};
  v4f a00 = z, a01 = z, a10 = z, a11 = z;

  v8s cur[8], nxt[8];
#pragma unroll
  for (int i = 0; i < 8; ++i) cur[i] = *(const v8s*)(base[i]);
#pragma unroll
  for (int i = 0; i < 8; ++i) nxt[i] = *(const v8s*)(base[i] + 32);

#pragma unroll 1
  for (int ks = 0; ks < 16; ++ks) {
    v8s nx2[8];
    if (ks < 14) {
      const int o = (ks + 2) * 32;
#pragma unroll
      for (int i = 0; i < 8; ++i) nx2[i] = *(const v8s*)(base[i] + o);
    }
    // Ah0,Ah1,Al0,Al1 = cur[0..3]; Bh0,Bh1,Bl0,Bl1 = cur[4..7]
    a00 = MFMA32(cur[2], cur[4], a00); a00 = MFMA32(cur[0], cur[6], a00); a00 = MFMA32(cur[0], cur[4], a00);
    a01 = MFMA32(cur[2], cur[5], a01); a01 = MFMA32(cur[0], cur[7], a01); a01 = MFMA32(cur[0], cur[5], a01);
    a10 = MFMA32(cur[3], cur[4], a10); a10 = MFMA32(cur[1], cur[6], a10); a10 = MFMA32(cur[1], cur[4], a10);
    a11 = MFMA32(cur[3], cur[5], a11); a11 = MFMA32(cur[1], cur[7], a11); a11 = MFMA32(cur[1], cur[5], a11);
#pragma unroll
    for (int i = 0; i < 8; ++i) { cur[i] = nxt[i]; nxt[i] = nx2[i]; }
  }

  v4f accs[2][2] = {{a00, a01}, {a10, a11}};
#pragma unroll
  for (int mt = 0; mt < 2; ++mt) {
#pragma unroll
    for (int nt = 0; nt < 2; ++nt) {
      const int n = bn * 32 + nt * 16 + c;
      const int which = n >> 9, cc = n & 511, h = cc >> 6, d = cc & 63;
      const float bv = bin[n];
#pragma unroll
      for (int r = 0; r < 4; ++r) {
        const int m = bm * 32 + mt * 16 + (q << 2) + r;
        const int b = (m >= 192) ? 1 : 0;
        const int tt = m - (b ? 192 : 0);
        const int bh = b * 8 + h;
        const float val = accs[mt][nt][r] + bv;
        const int rm = ((bh * 192 + tt) << 6) + d;
        if (which == 0)      wsf[rm] = val * QSCALE;
        else if (which == 1) wshd[rm] = f2bf(val);
        else if (which == 2) wshd[393216 + ((bh << 6) + d) * 192 + v1perm(tt)] = f2bf(val);
        else if (which == 3) wshd[196608 + rm] = f2bf(val);
        else wsf[196608 + ((bh * 192 + tt) * 16 + (d & 15)) * 4 + (d >> 4)] = val;
      }
    }
  }
}

// ------------------------------ Phase 2: attention -------------------------
// grid = 16(bh)*12(i)*4(ksplit) = 768 blocks, 256 thr (4 waves).
// Wave (jh = wv&1, kh = wv>>1): 6 jt (j-half) x 24 ksteps (k-half of the
// block's 48). Resident in regs: k1f[6][2] (48), vf[3][4] PV V1-frags (48,
// kstep-invariant, loaded once from global), q (16). Per kstep: K2 from LDS
// (broadcast), af build, per-m {2x2 L-MFMA, exp x8, pack, Pw turnaround,
// S-MFMA + 4 PV-MFMA}, then acc += o*v2. Partial (j-half,k-half) sums are
// combined by the existing cross-wave epilogue reduction.
__global__ __launch_bounds__(256, 2) void attn_kernel(
    const float* __restrict__ wsf, const unsigned short* __restrict__ wsh,
    float* __restrict__ accp, float* __restrict__ Sp) {
  __shared__ char smem[16640];
  unsigned short* K2s = (unsigned short*)smem;            // [48][64]

  const int tid  = threadIdx.x;
  const int wv   = tid >> 6;
  const int lane = tid & 63;
  const int c    = lane & 15;
  const int quad = lane >> 4;
  const int jh   = wv & 1;
  const int kh   = wv >> 1;

  const int bb = blockIdx.x;
  const int kb = bb & 3;
  const int it = (bb >> 2) % 12;
  const int bh = bb / 48;

  const unsigned short* k1g = wsh + bh * 192 * 64;
  const unsigned short* v1g = wsh + 393216 + bh * 64 * 192;
  const unsigned short* k2g = wsh + 196608 + bh * 192 * 64;
  const float*          v2g = wsf + 196608 + bh * 12288;   // [192][16][4]

  // stage this block's 48 k2 rows (only LDS staging left)
  for (int idx = tid; idx < 384; idx += 256) {
    const int r = idx >> 3, c8 = (idx & 7) * 8;
    *(uint4*)(K2s + r * 64 + c8) = *(const uint4*)(k2g + (kb * 48 + r) * 64 + c8);
  }

  // K1 B-frags (this wave's 6 jt): frag[j][h] = K1[(jh*6+j)*16+c][h*32+quad*8..+8]
  v8s k1f[6][2];
#pragma unroll
  for (int j = 0; j < 6; ++j) {
    const unsigned short* kp = k1g + (((jh * 6 + j) * 16 + c) << 6) + (quad << 3);
    k1f[j][0] = *(const v8s*)(kp);
    k1f[j][1] = *(const v8s*)(kp + 32);
  }

  // PV V1-frags (kstep-invariant): vf[m][t] = V1t[d=c+16t][chunk(jh*3+m) cols quad*8..+8]
  v8s vf[3][4];
#pragma unroll
  for (int m = 0; m < 3; ++m)
#pragma unroll
    for (int t = 0; t < 4; ++t)
      vf[m][t] = *(const v8s*)(v1g + (c + 16 * t) * 192 + ((jh * 3 + m) << 5) + (quad << 3));

  // q rows (fp32, pre-scaled): i = it*16+c, d = quad*8+e (+32)
  const float* qg = wsf + ((bh * 192 + it * 16 + c) << 6) + (quad << 3);
  float q0[8], q1[8];
  {
    v4f qa = *(const v4f*)(qg), qb = *(const v4f*)(qg + 4);
    v4f qc = *(const v4f*)(qg + 32), qd = *(const v4f*)(qg + 36);
#pragma unroll
    for (int e = 0; e < 4; ++e) {
      q0[e] = qa[e]; q0[4 + e] = qb[e];
      q1[e] = qc[e]; q1[4 + e] = qd[e];
    }
  }
  __syncthreads();   // K2s staged; no barriers until epilogue

  // Pw: per-wave [16 rows][20 dw] -- ONE m-block at a time (wave-sync turnaround)
  unsigned* Pw = (unsigned*)(smem + 6144) + wv * 320;
  const v4f z = {0.f, 0.f, 0.f, 0.f};
  v4f acc[4] = {z, z, z, z};
  v4f oS = z;
  const short one = (short)0x3F80;
  const v8s ones = {one, one, one, one, one, one, one, one};

  union U4 { uint4 u4; unsigned short us[8]; };
  union AF { v8s v; unsigned u[4]; };

#pragma unroll 1
  for (int ks = 0; ks < 24; ++ks) {
    const int rl = kh * 24 + ks;             // row in K2s / block-local k
    U4 kl, khh;
    kl.u4  = *(const uint4*)(K2s + (rl << 6) + (quad << 3));
    khh.u4 = *(const uint4*)(K2s + (rl << 6) + (quad << 3) + 32);
    const v4f v2v = *(const v4f*)(v2g + (((kb * 48 + rl) << 4) + c) * 4);

    AF af0, af1;  // A-frags: (q * k2) for d-halves 0/1
#pragma unroll
    for (int e = 0; e < 4; ++e) {
      af0.u[e] = pack_bf16(q0[2*e] * bf2f(kl.us[2*e]),  q0[2*e+1] * bf2f(kl.us[2*e+1]));
      af1.u[e] = pack_bf16(q1[2*e] * bf2f(khh.us[2*e]), q1[2*e+1] * bf2f(khh.us[2*e+1]));
    }

    v4f o0 = z, o1 = z, o2 = z, o3 = z;
#pragma unroll
    for (int m = 0; m < 3; ++m) {
      v4f Ca = MFMA32(af0.v, k1f[2*m][0], z);
      Ca = MFMA32(af1.v, k1f[2*m][1], Ca);
      v4f Cb = MFMA32(af0.v, k1f[2*m+1][0], z);
      Cb = MFMA32(af1.v, k1f[2*m+1][1], Cb);
#pragma unroll
      for (int r = 0; r < 4; ++r) { Ca[r] = EXP2F(Ca[r]); Cb[r] = EXP2F(Cb[r]); }
#pragma unroll
      for (int r = 0; r < 4; ++r)
        Pw[((quad << 2) + r) * 20 + c] = pack_bf16(Ca[r], Cb[r]);
      const v8s ap = *(const v8s*)(Pw + c * 20 + (quad << 2));
      oS = MFMA32(ap, ones, oS);
      o0 = MFMA32(ap, vf[m][0], o0);
      o1 = MFMA32(ap, vf[m][1], o1);
      o2 = MFMA32(ap, vf[m][2], o2);
      o3 = MFMA32(ap, vf[m][3], o3);
    }
    acc[0] += o0 * v2v[0];
    acc[1] += o1 * v2v[1];
    acc[2] += o2 * v2v[2];
    acc[3] += o3 * v2v[3];
  }

  __syncthreads();  // reuse smem for cross-wave reduction
  float* redA = (float*)smem;              // [4][16][64]
  float* redS = (float*)smem + 4096;       // [4][16]

  if (c == 0) {
    float* rs = redS + wv * 16 + (quad << 2);
#pragma unroll
    for (int r = 0; r < 4; ++r) rs[r] = oS[r];
  }
#pragma unroll
  for (int r = 0; r < 4; ++r) {
    float* rr = redA + wv * 1024 + (((quad << 2) + r) << 6) + c;
    rr[0] = acc[0][r]; rr[16] = acc[1][r]; rr[32] = acc[2][r]; rr[48] = acc[3][r];
  }
  __syncthreads();

  const int pbase = (bh * 12 + it) * 4 + kb;
  float* ap_out = accp + pbase * 1024;
  for (int idx = tid; idx < 1024; idx += 256)
    ap_out[idx] = redA[idx] + redA[1024 + idx] + redA[2048 + idx] + redA[3072 + idx];
  if (tid < 16)
    Sp[pbase * 16 + tid] = redS[tid] + redS[16 + tid] + redS[32 + tid] + redS[48 + tid];
}

// ------------------------------ Phase 2.5: normalize -----------------------
__global__ __launch_bounds__(256) void norm_kernel(
    const float* __restrict__ accp, const float* __restrict__ Sp,
    unsigned short* __restrict__ wsh) {
  const int flat = blockIdx.x * 2048 + threadIdx.x * 8;
  const int m = flat >> 9, cc = flat & 511;
  const int b = (m >= 192) ? 1 : 0;
  const int tt = m - (b ? 192 : 0);
  const int h = cc >> 6, d0 = cc & 63;
  const int bh = b * 8 + h, it = tt >> 4, i = tt & 15;
  const int pb = (bh * 12 + it) * 4;
  const float* ap = accp + pb * 1024 + (i << 6) + d0;
  v4f a0 = *(const v4f*)(ap), a1 = *(const v4f*)(ap + 4);
  float Sv = Sp[pb * 16 + i];
#pragma unroll
  for (int kb = 1; kb < 4; ++kb) {
    a0 += *(const v4f*)(ap + kb * 1024);
    a1 += *(const v4f*)(ap + kb * 1024 + 4);
    Sv += Sp[(pb + kb) * 16 + i];
  }
  const float inv = 1.0f / Sv;
  union { uint4 u; unsigned short us[8]; } ph, pl;
#pragma unroll
  for (int j = 0; j < 4; ++j) {
    float v = a0[j] * inv;
    unsigned short hh = f2bf(v);
    ph.us[j] = hh; pl.us[j] = f2bf(v - bf2f(hh));
    v = a1[j] * inv;
    hh = f2bf(v);
    ph.us[4 + j] = hh; pl.us[4 + j] = f2bf(v - bf2f(hh));
  }
  *(uint4*)(wsh + OH_OFF + flat) = ph.u;
  *(uint4*)(wsh + OL_OFF + flat) = pl.u;
}

// ------------------------------ Phase 3: out GEMM (bf16x3 MFMA) ------------
// grid 192 x 64thr: M=384 (12), N=512 (16), K=512, prefetch depth 2.
__global__ __launch_bounds__(64) void outp_kernel(
    const unsigned short* __restrict__ wsh, const float* __restrict__ bout,
    float* __restrict__ y) {
  const int lane = threadIdx.x;
  const int c = lane & 15, q = lane >> 4;
  const int bm = blockIdx.x % 12, bn = blockIdx.x / 12;

  const unsigned short* base[8];
  base[0] = wsh + OH_OFF + (bm * 32 + c) * 512 + (q << 3);
  base[1] = base[0] + 16 * 512;
  base[2] = wsh + OL_OFF + (bm * 32 + c) * 512 + (q << 3);
  base[3] = base[2] + 16 * 512;
  base[4] = wsh + WOTH_OFF + (bn * 32 + c) * 512 + (q << 3);
  base[5] = base[4] + 16 * 512;
  base[6] = wsh + WOTL_OFF + (bn * 32 + c) * 512 + (q << 3);
  base[7] = base[6] + 16 * 512;

  const v4f z = {0.f, 0.f, 0.f, 0.f};
  v4f a00 = z, a01 = z, a10 = z, a11 = z;

  v8s cur[8], nxt[8];
#pragma unroll
  for (int i = 0; i < 8; ++i) cur[i] = *(const v8s*)(base[i]);
#pragma unroll
  for (int i = 0; i < 8; ++i) nxt[i] = *(const v8s*)(base[i] + 32);

#pragma unroll 1
  for (int ks = 0; ks < 16; ++ks) {
    v8s nx2[8];
    if (ks < 14) {
      const int o = (ks + 2) * 32;
#pragma unroll
      for (int i = 0; i < 8; ++i) nx2[i] = *(const v8s*)(base[i] + o);
    }
    a00 = MFMA32(cur[2], cur[4], a00); a00 = MFMA32(cur[0], cur[6], a00); a00 = MFMA32(cur[0], cur[4], a00);
    a01 = MFMA32(cur[2], cur[5], a01); a01 = MFMA32(cur[0], cur[7], a01); a01 = MFMA32(cur[0], cur[5], a01);
    a10 = MFMA32(cur[3], cur[4], a10); a10 = MFMA32(cur[1], cur[6], a10); a10 = MFMA32(cur[1], cur[4], a10);
    a11 = MFMA32(cur[3], cur[5], a11); a11 = MFMA32(cur[1], cur[7], a11); a11 = MFMA32(cur[1], cur[5], a11);
#pragma unroll
    for (int i = 0; i < 8; ++i) { cur[i] = nxt[i]; nxt[i] = nx2[i]; }
  }

  v4f accs[2][2] = {{a00, a01}, {a10, a11}};
#pragma unroll
  for (int mt = 0; mt < 2; ++mt) {
#pragma unroll
    for (int nt = 0; nt < 2; ++nt) {
      const int n = bn * 32 + nt * 16 + c;
      const float bv = bout[n];
#pragma unroll
      for (int r = 0; r < 4; ++r) {
        const int m = bm * 32 + mt * 16 + (q << 2) + r;
        y[m * 512 + n] = accs[mt][nt][r] + bv;
      }
    }
  }
}

// ------------------------------ launcher -----------------------------------
extern "C" void kernel_launch(void* const* d_in, const int* in_sizes, int n_in,
                              void* d_out, int out_size, void* d_ws, size_t ws_size,
                              hipStream_t stream) {
  const float* x    = (const float*)d_in[0];
  const float* Win  = (const float*)d_in[1];
  const float* bin  = (const float*)d_in[2];
  const float* Wout = (const float*)d_in[3];
  const float* bout = (const float*)d_in[4];

  float* wsf = (float*)d_ws;
  unsigned short* wsh = (unsigned short*)(wsf + 1191936);
  float* accp = wsf + 393216;
  float* Sp   = wsf + 1179648;

  prep_kernel<<<dim3(864), 256, 0, stream>>>(x, Win, Wout, wsh);
  proj_kernel<<<dim3(960), 64, 0, stream>>>(wsh, bin, wsf, wsh);
  attn_kernel<<<dim3(768), 256, 0, stream>>>(wsf, wsh, accp, Sp);
  norm_kernel<<<dim3(96), 256, 0, stream>>>(accp, Sp, wsh);
  outp_kernel<<<dim3(192), 64, 0, stream>>>(wsh, bout, (float*)d_out);
}

// Round 6
// 143.759 us; speedup vs baseline: 1.0462x; 1.0462x over previous
//
#include <hip/hip_runtime.h>
#include <hip/hip_bf16.h>

// ---------------------------------------------------------------------------
// TwoSimplicialAttention  (B=2, T=192, C=512, H=8, D=64)
// R10: P never touches LDS. Logits MFMA operand-SWAPPED (mfma(k1,af)) so each
//      lane holds its own q-row's P slice: P[i=c][j=jt*16+quad*4+r]. PV is the
//      swapped mfma(vf, pp) computing out^T = V1^T P^T -- P goes MFMA-out ->
//      exp -> cvt_pk -> MFMA-in entirely in registers. v1perm changed so V1's
//      stored column order matches the lane position order (p=quad*8+hi*4+r).
//      S-sum = 8 scalar adds per m (P lane-local). v2p relaid [k][dt][cc] for
//      clean v4f loads. Per kstep removed: 12 ds_write + 3 ds_read_b128 +
//      3 lgkmcnt(0) stalls + 3 S-MFMAs. LDS = K2s + reduction = 17408 B.
// ---------------------------------------------------------------------------

typedef float  v4f __attribute__((ext_vector_type(4)));
typedef short  v8s __attribute__((ext_vector_type(8)));

__device__ __forceinline__ unsigned short f2bf(float f) {
  unsigned u = __float_as_uint(f);
  u += 0x7fffu + ((u >> 16) & 1u);       // RNE
  return (unsigned short)(u >> 16);
}
__device__ __forceinline__ float bf2f(unsigned short b) {
  return __uint_as_float(((unsigned)b) << 16);
}
__device__ __forceinline__ unsigned pack_bf16(float lo, float hi) {
  __hip_bfloat162 t = __float22bfloat162_rn(float2{lo, hi});
  union { __hip_bfloat162 b; unsigned u; } cv;
  cv.b = t;
  return cv.u;
}

#if __has_builtin(__builtin_amdgcn_exp2f)
#define EXP2F(x) __builtin_amdgcn_exp2f(x)
#else
#define EXP2F(x) exp2f(x)
#endif

#define MFMA32(a, b, c) __builtin_amdgcn_mfma_f32_16x16x32_bf16((a), (b), (c), 0, 0, 0)

// q scale = D^-0.5 * log2(e)
#define QSCALE 0.18033688011112042f

// ws layout, floats (wsf):
//   qs   [16][192][64]        @ 0        (q * 0.125*log2e, fp32)
//   v2p  [16][192][4][16]     @ 196608   ([.][k][dt][cc] = v2[d=cc+16dt], fp32)
//   accp [16][12][4][16][64]  @ 393216
//   Sp   [16][12][4][16]      @ 1179648  (total fp32: 1191936)
// ws layout, ushort (wsh = wsf + 1191936):
//   k1b  [16][192][64]  @ 0
//   k2b  [16][192][64]  @ 196608
//   v1t  [16][64][192]  @ 393216   (columns PERMUTED within 32-chunks)
//   xh   [384][512]     @ 589824      xl @ 786432
//   Wth  [2560][512]    @ 983040      Wtl @ 2293760   (W_in^T, k-major)
//   Woth [512][512]     @ 3604480     Wotl @ 3866624  (W_out^T, k-major)
//   oh   [384][512]     @ 4128768     ol  @ 4325376   (normalized out)

#define XH_OFF   589824
#define XL_OFF   786432
#define WTH_OFF  983040
#define WTL_OFF  2293760
#define WOTH_OFF 3604480
#define WOTL_OFF 3866624
#define OH_OFF   4128768
#define OL_OFF   4325376

// V1 column position for j-offset t within a 32-chunk (R10 ordering):
//   quad = (t>>2)&3, hi = (t>>4)&1, r = t&3  ->  p = quad*8 + hi*4 + r
// matches PV B-frag: lane(quad) element e: e<4 -> (hi=0,r=e), e>=4 -> (hi=1,r=e-4)
__device__ __forceinline__ int v1perm(int t) {
  return (t & ~31) | (((t >> 2) & 3) << 3) | (((t >> 4) & 1) << 2) | (t & 3);
}

// ------------------------------ Phase 0: prep ------------------------------
// grid 864: [0,640) W_in transpose+split (64n x 32k tiles), [640,768) W_out,
// [768,864) x hi/lo split. W goes through LDS so global writes are dense.
__global__ __launch_bounds__(256) void prep_kernel(
    const float* __restrict__ x, const float* __restrict__ Win,
    const float* __restrict__ Wout, unsigned short* __restrict__ wsh) {
  __shared__ float tile[32 * 65];
  const int bi = blockIdx.x, t = threadIdx.x;
  if (bi < 768) {
    const float* W; unsigned short *Th, *Tl; int R, n0, k0;
    if (bi < 640) {
      W = Win; Th = wsh + WTH_OFF; Tl = wsh + WTL_OFF; R = 2560;
      n0 = (bi % 40) << 6; k0 = (bi / 40) << 5;
    } else {
      const int idx = bi - 640;
      W = Wout; Th = wsh + WOTH_OFF; Tl = wsh + WOTL_OFF; R = 512;
      n0 = (idx & 7) << 6; k0 = (idx >> 3) << 5;
    }
    // phase 1: coalesced reads -> LDS [k][n] (pad 65)
    const int n = t & 63, kq = (t >> 6) * 8;
#pragma unroll
    for (int j = 0; j < 8; ++j)
      tile[(kq + j) * 65 + n] = W[(k0 + kq + j) * R + n0 + n];
    __syncthreads();
    // phase 2: k-contig hi/lo writes (dense 64B lines)
    const int n2 = t >> 2, ks = (t & 3) * 8;
    union { uint4 u; unsigned short us[8]; } ph, pl;
#pragma unroll
    for (int j = 0; j < 8; ++j) {
      const float v = tile[(ks + j) * 65 + n2];
      const unsigned short h = f2bf(v);
      ph.us[j] = h;
      pl.us[j] = f2bf(v - bf2f(h));
    }
    *(uint4*)(Th + (n0 + n2) * 512 + k0 + ks) = ph.u;
    *(uint4*)(Tl + (n0 + n2) * 512 + k0 + ks) = pl.u;
  } else {
    const int flat = ((bi - 768) * 256 + t) * 8;
    const v4f v0 = *(const v4f*)(x + flat);
    const v4f v1 = *(const v4f*)(x + flat + 4);
    union { uint4 u; unsigned short us[8]; } ph, pl;
#pragma unroll
    for (int j = 0; j < 4; ++j) {
      unsigned short h = f2bf(v0[j]);
      ph.us[j] = h; pl.us[j] = f2bf(v0[j] - bf2f(h));
      h = f2bf(v1[j]);
      ph.us[4 + j] = h; pl.us[4 + j] = f2bf(v1[j] - bf2f(h));
    }
    *(uint4*)(wsh + XH_OFF + flat) = ph.u;
    *(uint4*)(wsh + XL_OFF + flat) = pl.u;
  }
}

// ------------------------------ Phase 1: proj (bf16x3 MFMA) ----------------
// grid 960 x 64thr: 1 wave/block, 32x32 C-tile, prefetch depth 2.
__global__ __launch_bounds__(64) void proj_kernel(
    const unsigned short* __restrict__ wsh, const float* __restrict__ bin,
    float* __restrict__ wsf, unsigned short* __restrict__ wshd) {
  const int lane = threadIdx.x;
  const int c = lane & 15, q = lane >> 4;
  const int bm = blockIdx.x % 12, bn = blockIdx.x / 12;

  const unsigned short* base[8];
  base[0] = wsh + XH_OFF + (bm * 32 + c) * 512 + (q << 3);
  base[1] = base[0] + 16 * 512;
  base[2] = wsh + XL_OFF + (bm * 32 + c) * 512 + (q << 3);
  base[3] = base[2] + 16 * 512;
  base[4] = wsh + WTH_OFF + (bn * 32 + c) * 512 + (q << 3);
  base[5] = base[4] + 16 * 512;
  base[6] = wsh + WTL_OFF + (bn * 32 + c) * 512 + (q << 3);
  base[7] = base[6] + 16 * 512;

  const v4f z = {0.f, 0.f, 0.f, 0.f};
  v4f a00 = z, a01 = z, a10 = z, a11 = z;

  v8s cur[8], nxt[8];
#pragma unroll
  for (int i = 0; i < 8; ++i) cur[i] = *(const v8s*)(base[i]);
#pragma unroll
  for (int i = 0; i < 8; ++i) nxt[i] = *(const v8s*)(base[i] + 32);

#pragma unroll 1
  for (int ks = 0; ks < 16; ++ks) {
    v8s nx2[8];
    if (ks < 14) {
      const int o = (ks + 2) * 32;
#pragma unroll
      for (int i = 0; i < 8; ++i) nx2[i] = *(const v8s*)(base[i] + o);
    }
    // Ah0,Ah1,Al0,Al1 = cur[0..3]; Bh0,Bh1,Bl0,Bl1 = cur[4..7]
    a00 = MFMA32(cur[2], cur[4], a00); a00 = MFMA32(cur[0], cur[6], a00); a00 = MFMA32(cur[0], cur[4], a00);
    a01 = MFMA32(cur[2], cur[5], a01); a01 = MFMA32(cur[0], cur[7], a01); a01 = MFMA32(cur[0], cur[5], a01);
    a10 = MFMA32(cur[3], cur[4], a10); a10 = MFMA32(cur[1], cur[6], a10); a10 = MFMA32(cur[1], cur[4], a10);
    a11 = MFMA32(cur[3], cur[5], a11); a11 = MFMA32(cur[1], cur[7], a11); a11 = MFMA32(cur[1], cur[5], a11);
#pragma unroll
    for (int i = 0; i < 8; ++i) { cur[i] = nxt[i]; nxt[i] = nx2[i]; }
  }

  v4f accs[2][2] = {{a00, a01}, {a10, a11}};
#pragma unroll
  for (int mt = 0; mt < 2; ++mt) {
#pragma unroll
    for (int nt = 0; nt < 2; ++nt) {
      const int n = bn * 32 + nt * 16 + c;
      const int which = n >> 9, cc = n & 511, h = cc >> 6, d = cc & 63;
      const float bv = bin[n];
#pragma unroll
      for (int r = 0; r < 4; ++r) {
        const int m = bm * 32 + mt * 16 + (q << 2) + r;
        const int b = (m >= 192) ? 1 : 0;
        const int tt = m - (b ? 192 : 0);
        const int bh = b * 8 + h;
        const float val = accs[mt][nt][r] + bv;
        const int rm = ((bh * 192 + tt) << 6) + d;
        if (which == 0)      wsf[rm] = val * QSCALE;
        else if (which == 1) wshd[rm] = f2bf(val);
        else if (which == 2) wshd[393216 + ((bh << 6) + d) * 192 + v1perm(tt)] = f2bf(val);
        else if (which == 3) wshd[196608 + rm] = f2bf(val);
        else wsf[196608 + ((bh * 192 + tt) << 6) + ((d >> 4) << 4) + (d & 15)] = val;
      }
    }
  }
}

// ------------------------------ Phase 2: attention -------------------------
// grid = 16(bh)*12(i)*4(ksplit) = 768 blocks, 256 thr (4 waves).
// Wave (jh = wv&1, kh = wv>>1): 6 jt x 24 ksteps. Registers: k1f[6][2] (48),
// vf[3][4] (48, kstep-invariant), q (16), acc (16).
// Per kstep: K2 from LDS (broadcast); af build; per m (jt pair):
//   Ct = mfma(k1f, af)  -> lane holds P[i=c][j=jt*16+quad*4+r]  (swapped!)
//   exp -> sS adds -> cvt_pk into pp (PV B-frag, position = quad*8+hi*4+r)
//   o_dt = mfma(vf[m][dt], pp)  -> out^T, all in registers, zero LDS traffic.
// acc[dt] += o_dt * v2 (v2p layout [k][dt][cc] -> 4 v4f broadcast loads).
__global__ __launch_bounds__(256, 2) void attn_kernel(
    const float* __restrict__ wsf, const unsigned short* __restrict__ wsh,
    float* __restrict__ accp, float* __restrict__ Sp) {
  __shared__ char smem[17408];
  unsigned short* K2s = (unsigned short*)smem;            // [48][64]

  const int tid  = threadIdx.x;
  const int wv   = tid >> 6;
  const int lane = tid & 63;
  const int c    = lane & 15;
  const int quad = lane >> 4;
  const int jh   = wv & 1;
  const int kh   = wv >> 1;

  const int bb = blockIdx.x;
  const int kb = bb & 3;
  const int it = (bb >> 2) % 12;
  const int bh = bb / 48;

  const unsigned short* k1g = wsh + bh * 192 * 64;
  const unsigned short* v1g = wsh + 393216 + bh * 64 * 192;
  const unsigned short* k2g = wsh + 196608 + bh * 192 * 64;
  const float*          v2g = wsf + 196608 + bh * 12288;   // [192][4][16]

  // stage this block's 48 k2 rows (only LDS staging left)
  for (int idx = tid; idx < 384; idx += 256) {
    const int r = idx >> 3, c8 = (idx & 7) * 8;
    *(uint4*)(K2s + r * 64 + c8) = *(const uint4*)(k2g + (kb * 48 + r) * 64 + c8);
  }

  // K1 A-frags (this wave's 6 jt): frag[j][h] = K1[(jh*6+j)*16+c][h*32+quad*8..+8]
  v8s k1f[6][2];
#pragma unroll
  for (int j = 0; j < 6; ++j) {
    const unsigned short* kp = k1g + (((jh * 6 + j) * 16 + c) << 6) + (quad << 3);
    k1f[j][0] = *(const v8s*)(kp);
    k1f[j][1] = *(const v8s*)(kp + 32);
  }

  // PV A-frags (kstep-invariant): vf[m][dt] = V1t[d=dt*16+c][chunk(jh*3+m), pos quad*8..+8]
  v8s vf[3][4];
#pragma unroll
  for (int m = 0; m < 3; ++m)
#pragma unroll
    for (int dt = 0; dt < 4; ++dt)
      vf[m][dt] = *(const v8s*)(v1g + (dt * 16 + c) * 192 + ((jh * 3 + m) << 5) + (quad << 3));

  // q rows (fp32, pre-scaled): i = it*16+c, d = quad*8+e (+32)
  const float* qg = wsf + ((bh * 192 + it * 16 + c) << 6) + (quad << 3);
  float q0[8], q1[8];
  {
    v4f qa = *(const v4f*)(qg), qb = *(const v4f*)(qg + 4);
    v4f qc = *(const v4f*)(qg + 32), qd = *(const v4f*)(qg + 36);
#pragma unroll
    for (int e = 0; e < 4; ++e) {
      q0[e] = qa[e]; q0[4 + e] = qb[e];
      q1[e] = qc[e]; q1[4 + e] = qd[e];
    }
  }
  __syncthreads();   // K2s staged; no barriers until epilogue

  const v4f z = {0.f, 0.f, 0.f, 0.f};
  v4f acc[4] = {z, z, z, z};
  float sS = 0.f;

  union U4 { uint4 u4; unsigned short us[8]; };
  union AF { v8s v; unsigned u[4]; };

#pragma unroll 1
  for (int ks = 0; ks < 24; ++ks) {
    const int rl = kh * 24 + ks;             // row in K2s / block-local k
    U4 kl, khh;
    kl.u4  = *(const uint4*)(K2s + (rl << 6) + (quad << 3));
    khh.u4 = *(const uint4*)(K2s + (rl << 6) + (quad << 3) + 32);
    // v2: vt[dt][r] = v2[dt*16+quad*4+r]  (layout [k][dt][cc], broadcast loads)
    const float* vb = v2g + ((kb * 48 + rl) << 6) + (quad << 2);
    const v4f vt0 = *(const v4f*)(vb);
    const v4f vt1 = *(const v4f*)(vb + 16);
    const v4f vt2 = *(const v4f*)(vb + 32);
    const v4f vt3 = *(const v4f*)(vb + 48);

    AF af0, af1;  // B-frags of L-MFMA: (q*k2) for d-halves 0/1, col index = i = c
#pragma unroll
    for (int e = 0; e < 4; ++e) {
      af0.u[e] = pack_bf16(q0[2*e] * bf2f(kl.us[2*e]),  q0[2*e+1] * bf2f(kl.us[2*e+1]));
      af1.u[e] = pack_bf16(q1[2*e] * bf2f(khh.us[2*e]), q1[2*e+1] * bf2f(khh.us[2*e+1]));
    }

    v4f o0 = z, o1 = z, o2 = z, o3 = z;
#pragma unroll
    for (int m = 0; m < 3; ++m) {
      // SWAPPED logits: rows = k1 (j), cols = q (i); lane holds P[i=c][j=..quad*4+r]
      v4f Ca = MFMA32(k1f[2*m][0],   af0.v, z);
      Ca = MFMA32(k1f[2*m][1],   af1.v, Ca);
      v4f Cb = MFMA32(k1f[2*m+1][0], af0.v, z);
      Cb = MFMA32(k1f[2*m+1][1], af1.v, Cb);
#pragma unroll
      for (int r = 0; r < 4; ++r) { Ca[r] = EXP2F(Ca[r]); Cb[r] = EXP2F(Cb[r]); }
      sS += Ca[0] + Ca[1] + Ca[2] + Ca[3] + Cb[0] + Cb[1] + Cb[2] + Cb[3];
      AF pp;  // PV B-frag: pos e<4 -> jt-even r=e; e>=4 -> jt-odd r=e-4
      pp.u[0] = pack_bf16(Ca[0], Ca[1]);
      pp.u[1] = pack_bf16(Ca[2], Ca[3]);
      pp.u[2] = pack_bf16(Cb[0], Cb[1]);
      pp.u[3] = pack_bf16(Cb[2], Cb[3]);
      o0 = MFMA32(vf[m][0], pp.v, o0);
      o1 = MFMA32(vf[m][1], pp.v, o1);
      o2 = MFMA32(vf[m][2], pp.v, o2);
      o3 = MFMA32(vf[m][3], pp.v, o3);
    }
    acc[0] += o0 * vt0;
    acc[1] += o1 * vt1;
    acc[2] += o2 * vt2;
    acc[3] += o3 * vt3;
  }

  __syncthreads();  // reuse smem for cross-wave reduction
  float* redA = (float*)smem;              // [4][16 i][64 d]
  float* redS = (float*)smem + 4096;       // [4 wv][4 quad][16 i]

  // lane (c,quad): acc[dt][r] -> i=c, d=dt*16+quad*4+r (v4f rows contiguous)
#pragma unroll
  for (int dt = 0; dt < 4; ++dt)
    *(v4f*)(redA + wv * 1024 + (c << 6) + (dt << 4) + (quad << 2)) = acc[dt];
  redS[wv * 64 + (quad << 4) + c] = sS;
  __syncthreads();

  const int pbase = (bh * 12 + it) * 4 + kb;
  float* ap_out = accp + pbase * 1024;
  for (int idx = tid; idx < 1024; idx += 256)
    ap_out[idx] = redA[idx] + redA[1024 + idx] + redA[2048 + idx] + redA[3072 + idx];
  if (tid < 16) {
    float s = 0.f;
#pragma unroll
    for (int w = 0; w < 4; ++w)
#pragma unroll
      for (int qq = 0; qq < 4; ++qq)
        s += redS[w * 64 + qq * 16 + tid];
    Sp[pbase * 16 + tid] = s;
  }
}

// ------------------------------ Phase 2.5: normalize -----------------------
__global__ __launch_bounds__(256) void norm_kernel(
    const float* __restrict__ accp, const float* __restrict__ Sp,
    unsigned short* __restrict__ wsh) {
  const int flat = blockIdx.x * 2048 + threadIdx.x * 8;
  const int m = flat >> 9, cc = flat & 511;
  const int b = (m >= 192) ? 1 : 0;
  const int tt = m - (b ? 192 : 0);
  const int h = cc >> 6, d0 = cc & 63;
  const int bh = b * 8 + h, it = tt >> 4, i = tt & 15;
  const int pb = (bh * 12 + it) * 4;
  const float* ap = accp + pb * 1024 + (i << 6) + d0;
  v4f a0 = *(const v4f*)(ap), a1 = *(const v4f*)(ap + 4);
  float Sv = Sp[pb * 16 + i];
#pragma unroll
  for (int kb = 1; kb < 4; ++kb) {
    a0 += *(const v4f*)(ap + kb * 1024);
    a1 += *(const v4f*)(ap + kb * 1024 + 4);
    Sv += Sp[(pb + kb) * 16 + i];
  }
  const float inv = 1.0f / Sv;
  union { uint4 u; unsigned short us[8]; } ph, pl;
#pragma unroll
  for (int j = 0; j < 4; ++j) {
    float v = a0[j] * inv;
    unsigned short hh = f2bf(v);
    ph.us[j] = hh; pl.us[j] = f2bf(v - bf2f(hh));
    v = a1[j] * inv;
    hh = f2bf(v);
    ph.us[4 + j] = hh; pl.us[4 + j] = f2bf(v - bf2f(hh));
  }
  *(uint4*)(wsh + OH_OFF + flat) = ph.u;
  *(uint4*)(wsh + OL_OFF + flat) = pl.u;
}

// ------------------------------ Phase 3: out GEMM (bf16x3 MFMA) ------------
// grid 192 x 64thr: M=384 (12), N=512 (16), K=512, prefetch depth 2.
__global__ __launch_bounds__(64) void outp_kernel(
    const unsigned short* __restrict__ wsh, const float* __restrict__ bout,
    float* __restrict__ y) {
  const int lane = threadIdx.x;
  const int c = lane & 15, q = lane >> 4;
  const int bm = blockIdx.x % 12, bn = blockIdx.x / 12;

  const unsigned short* base[8];
  base[0] = wsh + OH_OFF + (bm * 32 + c) * 512 + (q << 3);
  base[1] = base[0] + 16 * 512;
  base[2] = wsh + OL_OFF + (bm * 32 + c) * 512 + (q << 3);
  base[3] = base[2] + 16 * 512;
  base[4] = wsh + WOTH_OFF + (bn * 32 + c) * 512 + (q << 3);
  base[5] = base[4] + 16 * 512;
  base[6] = wsh + WOTL_OFF + (bn * 32 + c) * 512 + (q << 3);
  base[7] = base[6] + 16 * 512;

  const v4f z = {0.f, 0.f, 0.f, 0.f};
  v4f a00 = z, a01 = z, a10 = z, a11 = z;

  v8s cur[8], nxt[8];
#pragma unroll
  for (int i = 0; i < 8; ++i) cur[i] = *(const v8s*)(base[i]);
#pragma unroll
  for (int i = 0; i < 8; ++i) nxt[i] = *(const v8s*)(base[i] + 32);

#pragma unroll 1
  for (int ks = 0; ks < 16; ++ks) {
    v8s nx2[8];
    if (ks < 14) {
      const int o = (ks + 2) * 32;
#pragma unroll
      for (int i = 0; i < 8; ++i) nx2[i] = *(const v8s*)(base[i] + o);
    }
    a00 = MFMA32(cur[2], cur[4], a00); a00 = MFMA32(cur[0], cur[6], a00); a00 = MFMA32(cur[0], cur[4], a00);
    a01 = MFMA32(cur[2], cur[5], a01); a01 = MFMA32(cur[0], cur[7], a01); a01 = MFMA32(cur[0], cur[5], a01);
    a10 = MFMA32(cur[3], cur[4], a10); a10 = MFMA32(cur[1], cur[6], a10); a10 = MFMA32(cur[1], cur[4], a10);
    a11 = MFMA32(cur[3], cur[5], a11); a11 = MFMA32(cur[1], cur[7], a11); a11 = MFMA32(cur[1], cur[5], a11);
#pragma unroll
    for (int i = 0; i < 8; ++i) { cur[i] = nxt[i]; nxt[i] = nx2[i]; }
  }

  v4f accs[2][2] = {{a00, a01}, {a10, a11}};
#pragma unroll
  for (int mt = 0; mt < 2; ++mt) {
#pragma unroll
    for (int nt = 0; nt < 2; ++nt) {
      const int n = bn * 32 + nt * 16 + c;
      const float bv = bout[n];
#pragma unroll
      for (int r = 0; r < 4; ++r) {
        const int m = bm * 32 + mt * 16 + (q << 2) + r;
        y[m * 512 + n] = accs[mt][nt][r] + bv;
      }
    }
  }
}

// ------------------------------ launcher -----------------------------------
extern "C" void kernel_launch(void* const* d_in, const int* in_sizes, int n_in,
                              void* d_out, int out_size, void* d_ws, size_t ws_size,
                              hipStream_t stream) {
  const float* x    = (const float*)d_in[0];
  const float* Win  = (const float*)d_in[1];
  const float* bin  = (const float*)d_in[2];
  const float* Wout = (const float*)d_in[3];
  const float* bout = (const float*)d_in[4];

  float* wsf = (float*)d_ws;
  unsigned short* wsh = (unsigned short*)(wsf + 1191936);
  float* accp = wsf + 393216;
  float* Sp   = wsf + 1179648;

  prep_kernel<<<dim3(864), 256, 0, stream>>>(x, Win, Wout, wsh);
  proj_kernel<<<dim3(960), 64, 0, stream>>>(wsh, bin, wsf, wsh);
  attn_kernel<<<dim3(768), 256, 0, stream>>>(wsf, wsh, accp, Sp);
  norm_kernel<<<dim3(96), 256, 0, stream>>>(accp, Sp, wsh);
  outp_kernel<<<dim3(192), 64, 0, stream>>>(wsh, bout, (float*)d_out);
}